// Round 1
// baseline (1000.959 us; speedup 1.0000x reference)
//
#include <hip/hip_runtime.h>

#define NN 50000
#define NE 1600000
#define DD 128
#define NL 4
#define NG 512

typedef __attribute__((ext_vector_type(8))) short short8;
typedef __attribute__((ext_vector_type(4))) float floatx4;

__device__ __forceinline__ unsigned short f2bf(float f) {
    unsigned int u = __float_as_uint(f);
    u += 0x7fffu + ((u >> 16) & 1u);
    return (unsigned short)(u >> 16);
}

// ---------- CSR build ----------
__global__ __launch_bounds__(256) void hist_kernel(const int* __restrict__ dst,
                                                   int* __restrict__ deg) {
    int e = blockIdx.x * 256 + threadIdx.x;
    if (e < NE) atomicAdd(&deg[dst[e]], 1);
}

__global__ __launch_bounds__(256) void scan_kernel(const int* __restrict__ deg,
                                                   int* __restrict__ rowptr) {
    const int CH = (NN + 255) / 256;  // 196
    __shared__ int sums[256];
    int t = threadIdx.x;
    int start = t * CH;
    int end = start + CH < NN ? start + CH : NN;
    int s = 0;
    for (int i = start; i < end; i++) s += deg[i];
    sums[t] = s;
    __syncthreads();
    for (int off = 1; off < 256; off <<= 1) {
        int v = (t >= off) ? sums[t - off] : 0;
        __syncthreads();
        sums[t] += v;
        __syncthreads();
    }
    int run = (t > 0) ? sums[t - 1] : 0;
    for (int i = start; i < end; i++) { rowptr[i] = run; run += deg[i]; }
    if (end == NN && start < NN) rowptr[NN] = run;  // only t=255
}

__global__ __launch_bounds__(256) void fill_kernel(const int* __restrict__ src,
                                                   const int* __restrict__ dst,
                                                   const int* __restrict__ rowptr,
                                                   int* __restrict__ fill,
                                                   int* __restrict__ col) {
    int e = blockIdx.x * 256 + threadIdx.x;
    if (e < NE) {
        int d = dst[e];
        int pos = atomicAdd(&fill[d], 1);
        col[rowptr[d] + pos] = src[e];
    }
}

// ---------- weight prep: fp32 [l][k][n] -> bf16 transposed [l][n][k] ----------
__global__ __launch_bounds__(256) void prep_kernel(const float* __restrict__ Ws1,
                                                   const float* __restrict__ Ws2,
                                                   unsigned short* __restrict__ W1T,
                                                   unsigned short* __restrict__ W2T) {
    int idx = blockIdx.x * 256 + threadIdx.x;  // [0, NL*DD*DD)
    int l = idx >> 14;
    int rem = idx & 16383;
    int k = rem >> 7;
    int n = rem & 127;
    int o = (l << 14) + (n << 7) + k;
    W1T[o] = f2bf(Ws1[idx]);
    W2T[o] = f2bf(Ws2[idx]);
}

// ---------- aggregation: hpre[i] = x[i] + sum_{j in N(i)} x[j] ----------
// 32 lanes per node, float4 per lane (32*4 = 128 = D)
__global__ __launch_bounds__(256) void agg_kernel(const float* __restrict__ x,
                                                  const int* __restrict__ rowptr,
                                                  const int* __restrict__ col,
                                                  float* __restrict__ hpre) {
    int g = threadIdx.x >> 5;
    int lane = threadIdx.x & 31;
    int node = blockIdx.x * 8 + g;
    const float* xr = x + (size_t)node * DD + lane * 4;
    float4 acc = *(const float4*)xr;
    int s = rowptr[node], e = rowptr[node + 1];
    for (int i = s; i < e; i++) {
        int j = col[i];
        float4 v = *(const float4*)(x + (size_t)j * DD + lane * 4);
        acc.x += v.x; acc.y += v.y; acc.z += v.z; acc.w += v.w;
    }
    *(float4*)(hpre + (size_t)node * DD + lane * 4) = acc;
}

// ---------- fused MLP: out = relu(A@W1+b1)@W2 + b2 (bf16 MFMA, fp32 accum) ----------
// 64 rows/block, 4 waves, wave w owns rows [16w,16w+16); 8 n-tiles per wave.
__global__ __launch_bounds__(256) void mlp_kernel(const float* __restrict__ A,
                                                  const unsigned short* __restrict__ W1T,
                                                  const float* __restrict__ b1,
                                                  const unsigned short* __restrict__ W2T,
                                                  const float* __restrict__ b2,
                                                  float* __restrict__ out) {
    __shared__ unsigned short Hs[64][136];  // +8 pad
    int tid = threadIdx.x;
    int w = tid >> 6;
    int lane = tid & 63;
    int quad = lane >> 4;
    int li = lane & 15;
    int row0 = blockIdx.x * 64;
    int arow = row0 + 16 * w + li;
    bool avalid = arow < NN;
    const float* arp = A + (size_t)arow * DD;

    floatx4 acc[8];
#pragma unroll
    for (int tn = 0; tn < 8; tn++) acc[tn] = (floatx4){0.f, 0.f, 0.f, 0.f};

#pragma unroll
    for (int kk = 0; kk < 4; kk++) {
        int k0 = kk * 32 + quad * 8;
        union { short8 v; unsigned short u[8]; } af;
        if (avalid) {
            float4 f0 = *(const float4*)(arp + k0);
            float4 f1 = *(const float4*)(arp + k0 + 4);
            af.u[0] = f2bf(f0.x); af.u[1] = f2bf(f0.y); af.u[2] = f2bf(f0.z); af.u[3] = f2bf(f0.w);
            af.u[4] = f2bf(f1.x); af.u[5] = f2bf(f1.y); af.u[6] = f2bf(f1.z); af.u[7] = f2bf(f1.w);
        } else {
            af.v = (short8){0, 0, 0, 0, 0, 0, 0, 0};
        }
#pragma unroll
        for (int tn = 0; tn < 8; tn++) {
            short8 bf = *(const short8*)(W1T + ((tn * 16 + li) << 7) + k0);
            acc[tn] = __builtin_amdgcn_mfma_f32_16x16x32_bf16(af.v, bf, acc[tn], 0, 0, 0);
        }
    }
    // epilogue A: relu(acc + b1) -> Hs (bf16, row-major for stage-B A-fragments)
#pragma unroll
    for (int tn = 0; tn < 8; tn++) {
        float bias = b1[tn * 16 + li];
#pragma unroll
        for (int r = 0; r < 4; r++) {
            float v = acc[tn][r] + bias;
            v = fmaxf(v, 0.f);
            Hs[16 * w + quad * 4 + r][tn * 16 + li] = f2bf(v);
        }
    }
    __syncthreads();

#pragma unroll
    for (int tn = 0; tn < 8; tn++) acc[tn] = (floatx4){0.f, 0.f, 0.f, 0.f};
#pragma unroll
    for (int kk = 0; kk < 4; kk++) {
        int k0 = kk * 32 + quad * 8;
        short8 af = *(const short8*)&Hs[16 * w + li][k0];
#pragma unroll
        for (int tn = 0; tn < 8; tn++) {
            short8 bf = *(const short8*)(W2T + ((tn * 16 + li) << 7) + k0);
            acc[tn] = __builtin_amdgcn_mfma_f32_16x16x32_bf16(af, bf, acc[tn], 0, 0, 0);
        }
    }
#pragma unroll
    for (int tn = 0; tn < 8; tn++) {
        float bias = b2[tn * 16 + li];
#pragma unroll
        for (int r = 0; r < 4; r++) {
            int grow = row0 + 16 * w + quad * 4 + r;
            if (grow < NN) out[(size_t)grow * DD + tn * 16 + li] = acc[tn][r] + bias;
        }
    }
}

// ---------- global add pool: batch sorted -> per-graph contiguous range ----------
__global__ __launch_bounds__(128) void pool_kernel(const float* __restrict__ x,
                                                   const int* __restrict__ batch,
                                                   float* __restrict__ out) {
    int g = blockIdx.x;
    int lo = 0, hi = NN;
    while (lo < hi) { int mid = (lo + hi) >> 1; if (batch[mid] < g) lo = mid + 1; else hi = mid; }
    int s = lo;
    hi = NN;
    while (lo < hi) { int mid = (lo + hi) >> 1; if (batch[mid] < g + 1) lo = mid + 1; else hi = mid; }
    int e = lo;
    int d = threadIdx.x;
    float acc = 0.f;
    for (int i = s; i < e; i++) acc += x[(size_t)i * DD + d];
    out[g * DD + d] = acc;
}

extern "C" void kernel_launch(void* const* d_in, const int* in_sizes, int n_in,
                              void* d_out, int out_size, void* d_ws, size_t ws_size,
                              hipStream_t stream) {
    const float* x0 = (const float*)d_in[0];
    const int* edge = (const int*)d_in[1];
    const int* batch = (const int*)d_in[2];
    const float* Ws1 = (const float*)d_in[3];
    const float* bs1 = (const float*)d_in[4];
    const float* Ws2 = (const float*)d_in[5];
    const float* bs2 = (const float*)d_in[6];
    float* out = (float*)d_out;
    const int* src = edge;
    const int* dst = edge + NE;

    char* ws = (char*)d_ws;
    size_t off = 0;
    auto alloc = [&](size_t bytes) {
        void* p = ws + off;
        off += (bytes + 255) & ~(size_t)255;
        return p;
    };
    float* xA = (float*)alloc((size_t)NN * DD * 4);
    float* xB = (float*)alloc((size_t)NN * DD * 4);
    float* hpre = (float*)alloc((size_t)NN * DD * 4);
    int* col = (int*)alloc((size_t)NE * 4);
    int* rowptr = (int*)alloc((size_t)(NN + 1) * 4);
    int* deg = (int*)alloc((size_t)(NN + 1) * 4);
    int* fill = (int*)alloc((size_t)(NN + 1) * 4);
    unsigned short* W1T = (unsigned short*)alloc((size_t)NL * DD * DD * 2);
    unsigned short* W2T = (unsigned short*)alloc((size_t)NL * DD * DD * 2);

    // deg and fill are adjacent aligned allocations: one memset covers both
    size_t degspan = (((size_t)(NN + 1) * 4 + 255) & ~(size_t)255);
    hipMemsetAsync(deg, 0, 2 * degspan, stream);

    hist_kernel<<<(NE + 255) / 256, 256, 0, stream>>>(dst, deg);
    scan_kernel<<<1, 256, 0, stream>>>(deg, rowptr);
    fill_kernel<<<(NE + 255) / 256, 256, 0, stream>>>(src, dst, rowptr, fill, col);
    prep_kernel<<<(NL * DD * DD) / 256, 256, 0, stream>>>(Ws1, Ws2, W1T, W2T);

    const float* xin = x0;
    float* bufs[2] = {xA, xB};
    for (int l = 0; l < NL; l++) {
        agg_kernel<<<NN / 8, 256, 0, stream>>>(xin, rowptr, col, hpre);
        float* xout = bufs[l & 1];
        mlp_kernel<<<(NN + 63) / 64, 256, 0, stream>>>(hpre, W1T + l * DD * DD, bs1 + l * DD,
                                                       W2T + l * DD * DD, bs2 + l * DD, xout);
        xin = xout;
    }
    pool_kernel<<<NG, 128, 0, stream>>>(xin, batch, out);
}

// Round 2
// 721.999 us; speedup vs baseline: 1.3864x; 1.3864x over previous
//
#include <hip/hip_runtime.h>

#define NN 50000
#define NE 1600000
#define DD 128
#define NL 4
#define NG 512

typedef __attribute__((ext_vector_type(8))) short short8;
typedef __attribute__((ext_vector_type(4))) float floatx4;

__device__ __forceinline__ unsigned short f2bf(float f) {
    unsigned int u = __float_as_uint(f);
    u += 0x7fffu + ((u >> 16) & 1u);
    return (unsigned short)(u >> 16);
}
__device__ __forceinline__ float bf2f(unsigned short u) {
    return __uint_as_float(((unsigned int)u) << 16);
}

// ---------- fp32 -> bf16 convert (layer-0 input) ----------
__global__ __launch_bounds__(256) void cvt_kernel(const float* __restrict__ x,
                                                  unsigned short* __restrict__ xbf) {
    int idx = blockIdx.x * 256 + threadIdx.x;  // one float4 per thread
    float4 f = ((const float4*)x)[idx];
    ushort4 o;
    o.x = f2bf(f.x); o.y = f2bf(f.y); o.z = f2bf(f.z); o.w = f2bf(f.w);
    ((ushort4*)xbf)[idx] = o;
}

// ---------- CSR build ----------
__global__ __launch_bounds__(256) void hist_kernel(const int* __restrict__ dst,
                                                   int* __restrict__ deg) {
    int e = blockIdx.x * 256 + threadIdx.x;
    if (e < NE) atomicAdd(&deg[dst[e]], 1);
}

__global__ __launch_bounds__(256) void scan_kernel(const int* __restrict__ deg,
                                                   int* __restrict__ rowptr) {
    const int CH = (NN + 255) / 256;  // 196
    __shared__ int sums[256];
    int t = threadIdx.x;
    int start = t * CH;
    int end = start + CH < NN ? start + CH : NN;
    int s = 0;
    for (int i = start; i < end; i++) s += deg[i];
    sums[t] = s;
    __syncthreads();
    for (int off = 1; off < 256; off <<= 1) {
        int v = (t >= off) ? sums[t - off] : 0;
        __syncthreads();
        sums[t] += v;
        __syncthreads();
    }
    int run = (t > 0) ? sums[t - 1] : 0;
    for (int i = start; i < end; i++) { rowptr[i] = run; run += deg[i]; }
    if (end == NN && start < NN) rowptr[NN] = run;  // only t=255
}

__global__ __launch_bounds__(256) void fill_kernel(const int* __restrict__ src,
                                                   const int* __restrict__ dst,
                                                   const int* __restrict__ rowptr,
                                                   int* __restrict__ fill,
                                                   int* __restrict__ col) {
    int e = blockIdx.x * 256 + threadIdx.x;
    if (e < NE) {
        int d = dst[e];
        int pos = atomicAdd(&fill[d], 1);
        col[rowptr[d] + pos] = src[e];
    }
}

// ---------- weight prep: fp32 [l][k][n] -> bf16 transposed [l][n][k] ----------
__global__ __launch_bounds__(256) void prep_kernel(const float* __restrict__ Ws1,
                                                   const float* __restrict__ Ws2,
                                                   unsigned short* __restrict__ W1T,
                                                   unsigned short* __restrict__ W2T) {
    int idx = blockIdx.x * 256 + threadIdx.x;  // [0, NL*DD*DD)
    int l = idx >> 14;
    int rem = idx & 16383;
    int k = rem >> 7;
    int n = rem & 127;
    int o = (l << 14) + (n << 7) + k;
    W1T[o] = f2bf(Ws1[idx]);
    W2T[o] = f2bf(Ws2[idx]);
}

// ---------- aggregation: hpre[i] = x[i] + sum_{j in N(i)} x[j], bf16 in/out ----------
// 32 lanes per node, ushort4 (4 ch) per lane; fp32 accumulation; edge loop x4 unroll
__global__ __launch_bounds__(256) void agg_kernel(const unsigned short* __restrict__ xbf,
                                                  const int* __restrict__ rowptr,
                                                  const int* __restrict__ col,
                                                  unsigned short* __restrict__ hpre) {
    int g = threadIdx.x >> 5;
    int lane = threadIdx.x & 31;
    int node = blockIdx.x * 8 + g;
    int co = lane * 4;
    float a0, a1, a2, a3;
    {
        ushort4 v = *(const ushort4*)(xbf + (size_t)node * DD + co);
        a0 = bf2f(v.x); a1 = bf2f(v.y); a2 = bf2f(v.z); a3 = bf2f(v.w);
    }
    int s = rowptr[node], e = rowptr[node + 1];
    int i = s;
    for (; i + 4 <= e; i += 4) {
        int j0 = col[i], j1 = col[i + 1], j2 = col[i + 2], j3 = col[i + 3];
        ushort4 v0 = *(const ushort4*)(xbf + (size_t)j0 * DD + co);
        ushort4 v1 = *(const ushort4*)(xbf + (size_t)j1 * DD + co);
        ushort4 v2 = *(const ushort4*)(xbf + (size_t)j2 * DD + co);
        ushort4 v3 = *(const ushort4*)(xbf + (size_t)j3 * DD + co);
        a0 += bf2f(v0.x) + bf2f(v1.x) + bf2f(v2.x) + bf2f(v3.x);
        a1 += bf2f(v0.y) + bf2f(v1.y) + bf2f(v2.y) + bf2f(v3.y);
        a2 += bf2f(v0.z) + bf2f(v1.z) + bf2f(v2.z) + bf2f(v3.z);
        a3 += bf2f(v0.w) + bf2f(v1.w) + bf2f(v2.w) + bf2f(v3.w);
    }
    for (; i < e; i++) {
        int j = col[i];
        ushort4 v = *(const ushort4*)(xbf + (size_t)j * DD + co);
        a0 += bf2f(v.x); a1 += bf2f(v.y); a2 += bf2f(v.z); a3 += bf2f(v.w);
    }
    ushort4 o;
    o.x = f2bf(a0); o.y = f2bf(a1); o.z = f2bf(a2); o.w = f2bf(a3);
    *(ushort4*)(hpre + (size_t)node * DD + co) = o;
}

// ---------- fused MLP: out = relu(A@W1+b1)@W2 + b2 (bf16 in/out, fp32 accum) ----------
// 64 rows/block, 4 waves, wave w owns rows [16w,16w+16); 8 n-tiles per wave.
__global__ __launch_bounds__(256) void mlp_kernel(const unsigned short* __restrict__ A,
                                                  const unsigned short* __restrict__ W1T,
                                                  const float* __restrict__ b1,
                                                  const unsigned short* __restrict__ W2T,
                                                  const float* __restrict__ b2,
                                                  unsigned short* __restrict__ out) {
    __shared__ unsigned short Hs[64][136];  // +8 pad
    int tid = threadIdx.x;
    int w = tid >> 6;
    int lane = tid & 63;
    int quad = lane >> 4;
    int li = lane & 15;
    int row0 = blockIdx.x * 64;
    int arow = row0 + 16 * w + li;
    bool avalid = arow < NN;
    const unsigned short* arp = A + (size_t)arow * DD;

    floatx4 acc[8];
#pragma unroll
    for (int tn = 0; tn < 8; tn++) acc[tn] = (floatx4){0.f, 0.f, 0.f, 0.f};

#pragma unroll
    for (int kk = 0; kk < 4; kk++) {
        int k0 = kk * 32 + quad * 8;
        short8 af = avalid ? *(const short8*)(arp + k0)
                           : (short8){0, 0, 0, 0, 0, 0, 0, 0};
#pragma unroll
        for (int tn = 0; tn < 8; tn++) {
            short8 bf = *(const short8*)(W1T + ((tn * 16 + li) << 7) + k0);
            acc[tn] = __builtin_amdgcn_mfma_f32_16x16x32_bf16(af, bf, acc[tn], 0, 0, 0);
        }
    }
    // epilogue A: relu(acc + b1) -> Hs (bf16, row-major for stage-B A-fragments)
#pragma unroll
    for (int tn = 0; tn < 8; tn++) {
        float bias = b1[tn * 16 + li];
#pragma unroll
        for (int r = 0; r < 4; r++) {
            float v = acc[tn][r] + bias;
            v = fmaxf(v, 0.f);
            Hs[16 * w + quad * 4 + r][tn * 16 + li] = f2bf(v);
        }
    }
    __syncthreads();

#pragma unroll
    for (int tn = 0; tn < 8; tn++) acc[tn] = (floatx4){0.f, 0.f, 0.f, 0.f};
#pragma unroll
    for (int kk = 0; kk < 4; kk++) {
        int k0 = kk * 32 + quad * 8;
        short8 af = *(const short8*)&Hs[16 * w + li][k0];
#pragma unroll
        for (int tn = 0; tn < 8; tn++) {
            short8 bf = *(const short8*)(W2T + ((tn * 16 + li) << 7) + k0);
            acc[tn] = __builtin_amdgcn_mfma_f32_16x16x32_bf16(af, bf, acc[tn], 0, 0, 0);
        }
    }
#pragma unroll
    for (int tn = 0; tn < 8; tn++) {
        float bias = b2[tn * 16 + li];
#pragma unroll
        for (int r = 0; r < 4; r++) {
            int grow = row0 + 16 * w + quad * 4 + r;
            if (grow < NN) out[(size_t)grow * DD + tn * 16 + li] = f2bf(acc[tn][r] + bias);
        }
    }
}

// ---------- global add pool: batch sorted -> per-graph contiguous range ----------
__global__ __launch_bounds__(128) void pool_kernel(const unsigned short* __restrict__ x,
                                                   const int* __restrict__ batch,
                                                   float* __restrict__ out) {
    int g = blockIdx.x;
    int lo = 0, hi = NN;
    while (lo < hi) { int mid = (lo + hi) >> 1; if (batch[mid] < g) lo = mid + 1; else hi = mid; }
    int s = lo;
    hi = NN;
    while (lo < hi) { int mid = (lo + hi) >> 1; if (batch[mid] < g + 1) lo = mid + 1; else hi = mid; }
    int e = lo;
    int d = threadIdx.x;
    float acc = 0.f;
    for (int i = s; i < e; i++) acc += bf2f(x[(size_t)i * DD + d]);
    out[g * DD + d] = acc;
}

extern "C" void kernel_launch(void* const* d_in, const int* in_sizes, int n_in,
                              void* d_out, int out_size, void* d_ws, size_t ws_size,
                              hipStream_t stream) {
    const float* x0 = (const float*)d_in[0];
    const int* edge = (const int*)d_in[1];
    const int* batch = (const int*)d_in[2];
    const float* Ws1 = (const float*)d_in[3];
    const float* bs1 = (const float*)d_in[4];
    const float* Ws2 = (const float*)d_in[5];
    const float* bs2 = (const float*)d_in[6];
    float* out = (float*)d_out;
    const int* src = edge;
    const int* dst = edge + NE;

    char* ws = (char*)d_ws;
    size_t off = 0;
    auto alloc = [&](size_t bytes) {
        void* p = ws + off;
        off += (bytes + 255) & ~(size_t)255;
        return p;
    };
    unsigned short* x0bf = (unsigned short*)alloc((size_t)NN * DD * 2);
    unsigned short* xA = (unsigned short*)alloc((size_t)NN * DD * 2);
    unsigned short* xB = (unsigned short*)alloc((size_t)NN * DD * 2);
    unsigned short* hpre = (unsigned short*)alloc((size_t)NN * DD * 2);
    int* col = (int*)alloc((size_t)NE * 4);
    int* rowptr = (int*)alloc((size_t)(NN + 1) * 4);
    int* deg = (int*)alloc((size_t)(NN + 1) * 4);
    int* fill = (int*)alloc((size_t)(NN + 1) * 4);
    unsigned short* W1T = (unsigned short*)alloc((size_t)NL * DD * DD * 2);
    unsigned short* W2T = (unsigned short*)alloc((size_t)NL * DD * DD * 2);

    // deg and fill are adjacent aligned allocations: one memset covers both
    size_t degspan = (((size_t)(NN + 1) * 4 + 255) & ~(size_t)255);
    hipMemsetAsync(deg, 0, 2 * degspan, stream);

    cvt_kernel<<<(NN * DD / 4) / 256, 256, 0, stream>>>(x0, x0bf);
    hist_kernel<<<(NE + 255) / 256, 256, 0, stream>>>(dst, deg);
    scan_kernel<<<1, 256, 0, stream>>>(deg, rowptr);
    fill_kernel<<<(NE + 255) / 256, 256, 0, stream>>>(src, dst, rowptr, fill, col);
    prep_kernel<<<(NL * DD * DD) / 256, 256, 0, stream>>>(Ws1, Ws2, W1T, W2T);

    const unsigned short* xin = x0bf;
    unsigned short* bufs[2] = {xA, xB};
    for (int l = 0; l < NL; l++) {
        agg_kernel<<<NN / 8, 256, 0, stream>>>(xin, rowptr, col, hpre);
        unsigned short* xout = bufs[l & 1];
        mlp_kernel<<<(NN + 63) / 64, 256, 0, stream>>>(hpre, W1T + l * DD * DD, bs1 + l * DD,
                                                       W2T + l * DD * DD, bs2 + l * DD, xout);
        xin = xout;
    }
    pool_kernel<<<NG, 128, 0, stream>>>(xin, batch, out);
}

// Round 3
// 657.496 us; speedup vs baseline: 1.5224x; 1.0981x over previous
//
#include <hip/hip_runtime.h>

#define NN 50000
#define NE 1600000
#define DD 128
#define NL 4
#define NG 512

typedef __attribute__((ext_vector_type(8))) short short8;
typedef __attribute__((ext_vector_type(4))) float floatx4;

__device__ __forceinline__ unsigned short f2bf(float f) {
    unsigned int u = __float_as_uint(f);
    u += 0x7fffu + ((u >> 16) & 1u);
    return (unsigned short)(u >> 16);
}
__device__ __forceinline__ float bf2f(unsigned short u) {
    return __uint_as_float(((unsigned int)u) << 16);
}

// ---------- fp32 -> bf16 convert (layer-0 input) ----------
__global__ __launch_bounds__(256) void cvt_kernel(const float* __restrict__ x,
                                                  unsigned short* __restrict__ xbf) {
    int idx = blockIdx.x * 256 + threadIdx.x;  // one float4 per thread
    float4 f = ((const float4*)x)[idx];
    ushort4 o;
    o.x = f2bf(f.x); o.y = f2bf(f.y); o.z = f2bf(f.z); o.w = f2bf(f.w);
    ((ushort4*)xbf)[idx] = o;
}

// ---------- CSR build ----------
// pos_kernel: one atomic pass gives per-edge slot AND per-node degree.
// 4 edges/thread (int4) -> 4 independent atomic chains to hide L2 round-trip.
__global__ __launch_bounds__(256) void pos_kernel(const int* __restrict__ dst,
                                                  int* __restrict__ deg,
                                                  int* __restrict__ pos) {
    int t = blockIdx.x * 256 + threadIdx.x;  // [0, NE/4)
    int4 d = ((const int4*)dst)[t];
    int4 p;
    p.x = atomicAdd(&deg[d.x], 1);
    p.y = atomicAdd(&deg[d.y], 1);
    p.z = atomicAdd(&deg[d.z], 1);
    p.w = atomicAdd(&deg[d.w], 1);
    ((int4*)pos)[t] = p;
}

__global__ __launch_bounds__(1024) void scan_kernel(const int* __restrict__ deg,
                                                    int* __restrict__ rowptr) {
    const int BS = 1024;
    const int CH = (NN + BS - 1) / BS;  // 49
    __shared__ int sums[BS];
    int t = threadIdx.x;
    int start = t * CH;
    int end = start + CH < NN ? start + CH : NN;
    int s = 0;
    for (int i = start; i < end; i++) s += deg[i];
    sums[t] = s;
    __syncthreads();
    for (int off = 1; off < BS; off <<= 1) {
        int v = (t >= off) ? sums[t - off] : 0;
        __syncthreads();
        sums[t] += v;
        __syncthreads();
    }
    int run = (t > 0) ? sums[t - 1] : 0;
    for (int i = start; i < end; i++) { rowptr[i] = run; run += deg[i]; }
    if (end == NN && start < NN) rowptr[NN] = run;  // only the last active thread
}

// atomic-free scatter: col[rowptr[d] + pos[e]] = src[e]; stores are fire-and-forget
__global__ __launch_bounds__(256) void fill_kernel(const int* __restrict__ src,
                                                   const int* __restrict__ dst,
                                                   const int* __restrict__ pos,
                                                   const int* __restrict__ rowptr,
                                                   int* __restrict__ col) {
    int t = blockIdx.x * 256 + threadIdx.x;  // [0, NE/4)
    int4 d = ((const int4*)dst)[t];
    int4 p = ((const int4*)pos)[t];
    int4 s = ((const int4*)src)[t];
    col[rowptr[d.x] + p.x] = s.x;
    col[rowptr[d.y] + p.y] = s.y;
    col[rowptr[d.z] + p.z] = s.z;
    col[rowptr[d.w] + p.w] = s.w;
}

// ---------- weight prep: fp32 [l][k][n] -> bf16 transposed [l][n][k] ----------
__global__ __launch_bounds__(256) void prep_kernel(const float* __restrict__ Ws1,
                                                   const float* __restrict__ Ws2,
                                                   unsigned short* __restrict__ W1T,
                                                   unsigned short* __restrict__ W2T) {
    int idx = blockIdx.x * 256 + threadIdx.x;  // [0, NL*DD*DD)
    int l = idx >> 14;
    int rem = idx & 16383;
    int k = rem >> 7;
    int n = rem & 127;
    int o = (l << 14) + (n << 7) + k;
    W1T[o] = f2bf(Ws1[idx]);
    W2T[o] = f2bf(Ws2[idx]);
}

// ---------- aggregation: hpre[i] = x[i] + sum_{j in N(i)} x[j], bf16 in/out ----------
// 32 lanes per node, ushort4 (4 ch) per lane; fp32 accumulation; edge loop x4 unroll
__global__ __launch_bounds__(256) void agg_kernel(const unsigned short* __restrict__ xbf,
                                                  const int* __restrict__ rowptr,
                                                  const int* __restrict__ col,
                                                  unsigned short* __restrict__ hpre) {
    int g = threadIdx.x >> 5;
    int lane = threadIdx.x & 31;
    int node = blockIdx.x * 8 + g;
    int co = lane * 4;
    float a0, a1, a2, a3;
    {
        ushort4 v = *(const ushort4*)(xbf + (size_t)node * DD + co);
        a0 = bf2f(v.x); a1 = bf2f(v.y); a2 = bf2f(v.z); a3 = bf2f(v.w);
    }
    int s = rowptr[node], e = rowptr[node + 1];
    int i = s;
    for (; i + 4 <= e; i += 4) {
        int j0 = col[i], j1 = col[i + 1], j2 = col[i + 2], j3 = col[i + 3];
        ushort4 v0 = *(const ushort4*)(xbf + (size_t)j0 * DD + co);
        ushort4 v1 = *(const ushort4*)(xbf + (size_t)j1 * DD + co);
        ushort4 v2 = *(const ushort4*)(xbf + (size_t)j2 * DD + co);
        ushort4 v3 = *(const ushort4*)(xbf + (size_t)j3 * DD + co);
        a0 += bf2f(v0.x) + bf2f(v1.x) + bf2f(v2.x) + bf2f(v3.x);
        a1 += bf2f(v0.y) + bf2f(v1.y) + bf2f(v2.y) + bf2f(v3.y);
        a2 += bf2f(v0.z) + bf2f(v1.z) + bf2f(v2.z) + bf2f(v3.z);
        a3 += bf2f(v0.w) + bf2f(v1.w) + bf2f(v2.w) + bf2f(v3.w);
    }
    for (; i < e; i++) {
        int j = col[i];
        ushort4 v = *(const ushort4*)(xbf + (size_t)j * DD + co);
        a0 += bf2f(v.x); a1 += bf2f(v.y); a2 += bf2f(v.z); a3 += bf2f(v.w);
    }
    ushort4 o;
    o.x = f2bf(a0); o.y = f2bf(a1); o.z = f2bf(a2); o.w = f2bf(a3);
    *(ushort4*)(hpre + (size_t)node * DD + co) = o;
}

// ---------- fused MLP: out = relu(A@W1+b1)@W2 + b2 (bf16 in/out, fp32 accum) ----------
// 64 rows/block, 4 waves, wave w owns rows [16w,16w+16); 8 n-tiles per wave.
__global__ __launch_bounds__(256) void mlp_kernel(const unsigned short* __restrict__ A,
                                                  const unsigned short* __restrict__ W1T,
                                                  const float* __restrict__ b1,
                                                  const unsigned short* __restrict__ W2T,
                                                  const float* __restrict__ b2,
                                                  unsigned short* __restrict__ out) {
    __shared__ unsigned short Hs[64][136];  // +8 pad
    int tid = threadIdx.x;
    int w = tid >> 6;
    int lane = tid & 63;
    int quad = lane >> 4;
    int li = lane & 15;
    int row0 = blockIdx.x * 64;
    int arow = row0 + 16 * w + li;
    bool avalid = arow < NN;
    const unsigned short* arp = A + (size_t)arow * DD;

    floatx4 acc[8];
#pragma unroll
    for (int tn = 0; tn < 8; tn++) acc[tn] = (floatx4){0.f, 0.f, 0.f, 0.f};

#pragma unroll
    for (int kk = 0; kk < 4; kk++) {
        int k0 = kk * 32 + quad * 8;
        short8 af = avalid ? *(const short8*)(arp + k0)
                           : (short8){0, 0, 0, 0, 0, 0, 0, 0};
#pragma unroll
        for (int tn = 0; tn < 8; tn++) {
            short8 bf = *(const short8*)(W1T + ((tn * 16 + li) << 7) + k0);
            acc[tn] = __builtin_amdgcn_mfma_f32_16x16x32_bf16(af, bf, acc[tn], 0, 0, 0);
        }
    }
    // epilogue A: relu(acc + b1) -> Hs (bf16, row-major for stage-B A-fragments)
#pragma unroll
    for (int tn = 0; tn < 8; tn++) {
        float bias = b1[tn * 16 + li];
#pragma unroll
        for (int r = 0; r < 4; r++) {
            float v = acc[tn][r] + bias;
            v = fmaxf(v, 0.f);
            Hs[16 * w + quad * 4 + r][tn * 16 + li] = f2bf(v);
        }
    }
    __syncthreads();

#pragma unroll
    for (int tn = 0; tn < 8; tn++) acc[tn] = (floatx4){0.f, 0.f, 0.f, 0.f};
#pragma unroll
    for (int kk = 0; kk < 4; kk++) {
        int k0 = kk * 32 + quad * 8;
        short8 af = *(const short8*)&Hs[16 * w + li][k0];
#pragma unroll
        for (int tn = 0; tn < 8; tn++) {
            short8 bf = *(const short8*)(W2T + ((tn * 16 + li) << 7) + k0);
            acc[tn] = __builtin_amdgcn_mfma_f32_16x16x32_bf16(af, bf, acc[tn], 0, 0, 0);
        }
    }
#pragma unroll
    for (int tn = 0; tn < 8; tn++) {
        float bias = b2[tn * 16 + li];
#pragma unroll
        for (int r = 0; r < 4; r++) {
            int grow = row0 + 16 * w + quad * 4 + r;
            if (grow < NN) out[(size_t)grow * DD + tn * 16 + li] = f2bf(acc[tn][r] + bias);
        }
    }
}

// ---------- global add pool: batch sorted -> per-graph contiguous range ----------
__global__ __launch_bounds__(128) void pool_kernel(const unsigned short* __restrict__ x,
                                                   const int* __restrict__ batch,
                                                   float* __restrict__ out) {
    int g = blockIdx.x;
    int lo = 0, hi = NN;
    while (lo < hi) { int mid = (lo + hi) >> 1; if (batch[mid] < g) lo = mid + 1; else hi = mid; }
    int s = lo;
    hi = NN;
    while (lo < hi) { int mid = (lo + hi) >> 1; if (batch[mid] < g + 1) lo = mid + 1; else hi = mid; }
    int e = lo;
    int d = threadIdx.x;
    float acc = 0.f;
    for (int i = s; i < e; i++) acc += bf2f(x[(size_t)i * DD + d]);
    out[g * DD + d] = acc;
}

extern "C" void kernel_launch(void* const* d_in, const int* in_sizes, int n_in,
                              void* d_out, int out_size, void* d_ws, size_t ws_size,
                              hipStream_t stream) {
    const float* x0 = (const float*)d_in[0];
    const int* edge = (const int*)d_in[1];
    const int* batch = (const int*)d_in[2];
    const float* Ws1 = (const float*)d_in[3];
    const float* bs1 = (const float*)d_in[4];
    const float* Ws2 = (const float*)d_in[5];
    const float* bs2 = (const float*)d_in[6];
    float* out = (float*)d_out;
    const int* src = edge;
    const int* dst = edge + NE;

    char* ws = (char*)d_ws;
    size_t off = 0;
    auto alloc = [&](size_t bytes) {
        void* p = ws + off;
        off += (bytes + 255) & ~(size_t)255;
        return p;
    };
    unsigned short* x0bf = (unsigned short*)alloc((size_t)NN * DD * 2);
    unsigned short* xA = (unsigned short*)alloc((size_t)NN * DD * 2);
    unsigned short* xB = (unsigned short*)alloc((size_t)NN * DD * 2);
    unsigned short* hpre = (unsigned short*)alloc((size_t)NN * DD * 2);
    int* col = (int*)alloc((size_t)NE * 4);
    int* pos = (int*)alloc((size_t)NE * 4);
    int* rowptr = (int*)alloc((size_t)(NN + 1) * 4);
    int* deg = (int*)alloc((size_t)(NN + 1) * 4);
    unsigned short* W1T = (unsigned short*)alloc((size_t)NL * DD * DD * 2);
    unsigned short* W2T = (unsigned short*)alloc((size_t)NL * DD * DD * 2);

    hipMemsetAsync(deg, 0, (size_t)(NN + 1) * 4, stream);

    cvt_kernel<<<(NN * DD / 4) / 256, 256, 0, stream>>>(x0, x0bf);
    pos_kernel<<<(NE / 4) / 256, 256, 0, stream>>>(dst, deg, pos);
    scan_kernel<<<1, 1024, 0, stream>>>(deg, rowptr);
    fill_kernel<<<(NE / 4) / 256, 256, 0, stream>>>(src, dst, pos, rowptr, col);
    prep_kernel<<<(NL * DD * DD) / 256, 256, 0, stream>>>(Ws1, Ws2, W1T, W2T);

    const unsigned short* xin = x0bf;
    unsigned short* bufs[2] = {xA, xB};
    for (int l = 0; l < NL; l++) {
        agg_kernel<<<NN / 8, 256, 0, stream>>>(xin, rowptr, col, hpre);
        unsigned short* xout = bufs[l & 1];
        mlp_kernel<<<(NN + 63) / 64, 256, 0, stream>>>(hpre, W1T + l * DD * DD, bs1 + l * DD,
                                                       W2T + l * DD * DD, bs2 + l * DD, xout);
        xin = xout;
    }
    pool_kernel<<<NG, 128, 0, stream>>>(xin, batch, out);
}

// Round 4
// 586.095 us; speedup vs baseline: 1.7078x; 1.1218x over previous
//
#include <hip/hip_runtime.h>

#define NN 50000
#define NE 1600000
#define DD 128
#define NL 4
#define NG 512
#define NT 196  // ceil(NN/256)

typedef __attribute__((ext_vector_type(8))) short short8;
typedef __attribute__((ext_vector_type(4))) float floatx4;

__device__ __forceinline__ unsigned short f2bf(float f) {
    unsigned int u = __float_as_uint(f);
    u += 0x7fffu + ((u >> 16) & 1u);
    return (unsigned short)(u >> 16);
}
__device__ __forceinline__ float bf2f(unsigned short u) {
    return __uint_as_float(((unsigned int)u) << 16);
}

// ---------- fp32 -> bf16 convert (layer-0 input) ----------
__global__ __launch_bounds__(256) void cvt_kernel(const float* __restrict__ x,
                                                  unsigned short* __restrict__ xbf) {
    int idx = blockIdx.x * 256 + threadIdx.x;  // one float4 per thread
    float4 f = ((const float4*)x)[idx];
    ushort4 o;
    o.x = f2bf(f.x); o.y = f2bf(f.y); o.z = f2bf(f.z); o.w = f2bf(f.w);
    ((ushort4*)xbf)[idx] = o;
}

// ---------- CSR build ----------
// pos_kernel: one atomic pass gives per-edge slot AND per-node degree.
// 4 edges/thread (int4) -> 4 independent atomic chains to hide L2 round-trip.
__global__ __launch_bounds__(256) void pos_kernel(const int* __restrict__ dst,
                                                  int* __restrict__ deg,
                                                  int* __restrict__ pos) {
    int t = blockIdx.x * 256 + threadIdx.x;  // [0, NE/4)
    int4 d = ((const int4*)dst)[t];
    int4 p;
    p.x = atomicAdd(&deg[d.x], 1);
    p.y = atomicAdd(&deg[d.y], 1);
    p.z = atomicAdd(&deg[d.z], 1);
    p.w = atomicAdd(&deg[d.w], 1);
    ((int4*)pos)[t] = p;
}

// ---------- parallel exclusive scan of deg -> rowptr (3 kernels, full-chip) ----------
__global__ __launch_bounds__(256) void tilesum_kernel(const int* __restrict__ deg,
                                                      int* __restrict__ tilesum) {
    int i = blockIdx.x * 256 + threadIdx.x;
    int v = (i < NN) ? deg[i] : 0;
    __shared__ int s[256];
    s[threadIdx.x] = v;
    __syncthreads();
    for (int off = 128; off > 0; off >>= 1) {
        if (threadIdx.x < off) s[threadIdx.x] += s[threadIdx.x + off];
        __syncthreads();
    }
    if (threadIdx.x == 0) tilesum[blockIdx.x] = s[0];
}

__global__ __launch_bounds__(256) void tilescan_kernel(const int* __restrict__ tilesum,
                                                       int* __restrict__ tileoff,
                                                       int* __restrict__ rowptr) {
    int t = threadIdx.x;
    __shared__ int s[256];
    int v = (t < NT) ? tilesum[t] : 0;
    s[t] = v;
    __syncthreads();
    for (int off = 1; off < 256; off <<= 1) {
        int u = (t >= off) ? s[t - off] : 0;
        __syncthreads();
        s[t] += u;
        __syncthreads();
    }
    if (t < NT) tileoff[t] = s[t] - v;   // exclusive tile offset
    if (t == NT - 1) rowptr[NN] = s[t];  // grand total
}

__global__ __launch_bounds__(256) void rowptr_kernel(const int* __restrict__ deg,
                                                     const int* __restrict__ tileoff,
                                                     int* __restrict__ rowptr) {
    int i = blockIdx.x * 256 + threadIdx.x;
    int t = threadIdx.x;
    int v = (i < NN) ? deg[i] : 0;
    __shared__ int s[256];
    s[t] = v;
    __syncthreads();
    for (int off = 1; off < 256; off <<= 1) {
        int u = (t >= off) ? s[t - off] : 0;
        __syncthreads();
        s[t] += u;
        __syncthreads();
    }
    if (i < NN) rowptr[i] = tileoff[blockIdx.x] + s[t] - v;
}

// atomic-free scatter: col[rowptr[d] + pos[e]] = src[e]; stores are fire-and-forget
__global__ __launch_bounds__(256) void fill_kernel(const int* __restrict__ src,
                                                   const int* __restrict__ dst,
                                                   const int* __restrict__ pos,
                                                   const int* __restrict__ rowptr,
                                                   int* __restrict__ col) {
    int t = blockIdx.x * 256 + threadIdx.x;  // [0, NE/4)
    int4 d = ((const int4*)dst)[t];
    int4 p = ((const int4*)pos)[t];
    int4 s = ((const int4*)src)[t];
    col[rowptr[d.x] + p.x] = s.x;
    col[rowptr[d.y] + p.y] = s.y;
    col[rowptr[d.z] + p.z] = s.z;
    col[rowptr[d.w] + p.w] = s.w;
}

// ---------- weight prep: fp32 [l][k][n] -> bf16 transposed [l][n][k] ----------
__global__ __launch_bounds__(256) void prep_kernel(const float* __restrict__ Ws1,
                                                   const float* __restrict__ Ws2,
                                                   unsigned short* __restrict__ W1T,
                                                   unsigned short* __restrict__ W2T) {
    int idx = blockIdx.x * 256 + threadIdx.x;  // [0, NL*DD*DD)
    int l = idx >> 14;
    int rem = idx & 16383;
    int k = rem >> 7;
    int n = rem & 127;
    int o = (l << 14) + (n << 7) + k;
    W1T[o] = f2bf(Ws1[idx]);
    W2T[o] = f2bf(Ws2[idx]);
}

// ---------- aggregation: hpre[i] = x[i] + sum_{j in N(i)} x[j], bf16 in/out ----------
// 32 lanes per node, ushort4 (4 ch) per lane; fp32 accumulation; edge loop x4 unroll
__global__ __launch_bounds__(256) void agg_kernel(const unsigned short* __restrict__ xbf,
                                                  const int* __restrict__ rowptr,
                                                  const int* __restrict__ col,
                                                  unsigned short* __restrict__ hpre) {
    int g = threadIdx.x >> 5;
    int lane = threadIdx.x & 31;
    int node = blockIdx.x * 8 + g;
    int co = lane * 4;
    float a0, a1, a2, a3;
    {
        ushort4 v = *(const ushort4*)(xbf + (size_t)node * DD + co);
        a0 = bf2f(v.x); a1 = bf2f(v.y); a2 = bf2f(v.z); a3 = bf2f(v.w);
    }
    int s = rowptr[node], e = rowptr[node + 1];
    int i = s;
    for (; i + 4 <= e; i += 4) {
        int j0 = col[i], j1 = col[i + 1], j2 = col[i + 2], j3 = col[i + 3];
        ushort4 v0 = *(const ushort4*)(xbf + (size_t)j0 * DD + co);
        ushort4 v1 = *(const ushort4*)(xbf + (size_t)j1 * DD + co);
        ushort4 v2 = *(const ushort4*)(xbf + (size_t)j2 * DD + co);
        ushort4 v3 = *(const ushort4*)(xbf + (size_t)j3 * DD + co);
        a0 += bf2f(v0.x) + bf2f(v1.x) + bf2f(v2.x) + bf2f(v3.x);
        a1 += bf2f(v0.y) + bf2f(v1.y) + bf2f(v2.y) + bf2f(v3.y);
        a2 += bf2f(v0.z) + bf2f(v1.z) + bf2f(v2.z) + bf2f(v3.z);
        a3 += bf2f(v0.w) + bf2f(v1.w) + bf2f(v2.w) + bf2f(v3.w);
    }
    for (; i < e; i++) {
        int j = col[i];
        ushort4 v = *(const ushort4*)(xbf + (size_t)j * DD + co);
        a0 += bf2f(v.x); a1 += bf2f(v.y); a2 += bf2f(v.z); a3 += bf2f(v.w);
    }
    ushort4 o;
    o.x = f2bf(a0); o.y = f2bf(a1); o.z = f2bf(a2); o.w = f2bf(a3);
    *(ushort4*)(hpre + (size_t)node * DD + co) = o;
}

// ---------- fused MLP: out = relu(A@W1+b1)@W2 + b2 (bf16 in/out, fp32 accum) ----------
// 64 rows/block, 4 waves, wave w owns rows [16w,16w+16); 8 n-tiles per wave.
__global__ __launch_bounds__(256) void mlp_kernel(const unsigned short* __restrict__ A,
                                                  const unsigned short* __restrict__ W1T,
                                                  const float* __restrict__ b1,
                                                  const unsigned short* __restrict__ W2T,
                                                  const float* __restrict__ b2,
                                                  unsigned short* __restrict__ out) {
    __shared__ unsigned short Hs[64][136];  // +8 pad
    int tid = threadIdx.x;
    int w = tid >> 6;
    int lane = tid & 63;
    int quad = lane >> 4;
    int li = lane & 15;
    int row0 = blockIdx.x * 64;
    int arow = row0 + 16 * w + li;
    bool avalid = arow < NN;
    const unsigned short* arp = A + (size_t)arow * DD;

    floatx4 acc[8];
#pragma unroll
    for (int tn = 0; tn < 8; tn++) acc[tn] = (floatx4){0.f, 0.f, 0.f, 0.f};

#pragma unroll
    for (int kk = 0; kk < 4; kk++) {
        int k0 = kk * 32 + quad * 8;
        short8 af = avalid ? *(const short8*)(arp + k0)
                           : (short8){0, 0, 0, 0, 0, 0, 0, 0};
#pragma unroll
        for (int tn = 0; tn < 8; tn++) {
            short8 bf = *(const short8*)(W1T + ((tn * 16 + li) << 7) + k0);
            acc[tn] = __builtin_amdgcn_mfma_f32_16x16x32_bf16(af, bf, acc[tn], 0, 0, 0);
        }
    }
    // epilogue A: relu(acc + b1) -> Hs (bf16, row-major for stage-B A-fragments)
#pragma unroll
    for (int tn = 0; tn < 8; tn++) {
        float bias = b1[tn * 16 + li];
#pragma unroll
        for (int r = 0; r < 4; r++) {
            float v = acc[tn][r] + bias;
            v = fmaxf(v, 0.f);
            Hs[16 * w + quad * 4 + r][tn * 16 + li] = f2bf(v);
        }
    }
    __syncthreads();

#pragma unroll
    for (int tn = 0; tn < 8; tn++) acc[tn] = (floatx4){0.f, 0.f, 0.f, 0.f};
#pragma unroll
    for (int kk = 0; kk < 4; kk++) {
        int k0 = kk * 32 + quad * 8;
        short8 af = *(const short8*)&Hs[16 * w + li][k0];
#pragma unroll
        for (int tn = 0; tn < 8; tn++) {
            short8 bf = *(const short8*)(W2T + ((tn * 16 + li) << 7) + k0);
            acc[tn] = __builtin_amdgcn_mfma_f32_16x16x32_bf16(af, bf, acc[tn], 0, 0, 0);
        }
    }
#pragma unroll
    for (int tn = 0; tn < 8; tn++) {
        float bias = b2[tn * 16 + li];
#pragma unroll
        for (int r = 0; r < 4; r++) {
            int grow = row0 + 16 * w + quad * 4 + r;
            if (grow < NN) out[(size_t)grow * DD + tn * 16 + li] = f2bf(acc[tn][r] + bias);
        }
    }
}

// ---------- global add pool: batch sorted -> per-graph contiguous range ----------
__global__ __launch_bounds__(128) void pool_kernel(const unsigned short* __restrict__ x,
                                                   const int* __restrict__ batch,
                                                   float* __restrict__ out) {
    int g = blockIdx.x;
    int lo = 0, hi = NN;
    while (lo < hi) { int mid = (lo + hi) >> 1; if (batch[mid] < g) lo = mid + 1; else hi = mid; }
    int s = lo;
    hi = NN;
    while (lo < hi) { int mid = (lo + hi) >> 1; if (batch[mid] < g + 1) lo = mid + 1; else hi = mid; }
    int e = lo;
    int d = threadIdx.x;
    float acc = 0.f;
    for (int i = s; i < e; i++) acc += bf2f(x[(size_t)i * DD + d]);
    out[g * DD + d] = acc;
}

extern "C" void kernel_launch(void* const* d_in, const int* in_sizes, int n_in,
                              void* d_out, int out_size, void* d_ws, size_t ws_size,
                              hipStream_t stream) {
    const float* x0 = (const float*)d_in[0];
    const int* edge = (const int*)d_in[1];
    const int* batch = (const int*)d_in[2];
    const float* Ws1 = (const float*)d_in[3];
    const float* bs1 = (const float*)d_in[4];
    const float* Ws2 = (const float*)d_in[5];
    const float* bs2 = (const float*)d_in[6];
    float* out = (float*)d_out;
    const int* src = edge;
    const int* dst = edge + NE;

    char* ws = (char*)d_ws;
    size_t off = 0;
    auto alloc = [&](size_t bytes) {
        void* p = ws + off;
        off += (bytes + 255) & ~(size_t)255;
        return p;
    };
    unsigned short* x0bf = (unsigned short*)alloc((size_t)NN * DD * 2);
    unsigned short* xA = (unsigned short*)alloc((size_t)NN * DD * 2);
    unsigned short* xB = (unsigned short*)alloc((size_t)NN * DD * 2);
    unsigned short* hpre = (unsigned short*)alloc((size_t)NN * DD * 2);
    int* col = (int*)alloc((size_t)NE * 4);
    int* pos = (int*)alloc((size_t)NE * 4);
    int* rowptr = (int*)alloc((size_t)(NN + 1) * 4);
    int* deg = (int*)alloc((size_t)(NN + 1) * 4);
    int* tilesum = (int*)alloc((size_t)NT * 4);
    int* tileoff = (int*)alloc((size_t)NT * 4);
    unsigned short* W1T = (unsigned short*)alloc((size_t)NL * DD * DD * 2);
    unsigned short* W2T = (unsigned short*)alloc((size_t)NL * DD * DD * 2);

    hipMemsetAsync(deg, 0, (size_t)(NN + 1) * 4, stream);

    cvt_kernel<<<(NN * DD / 4) / 256, 256, 0, stream>>>(x0, x0bf);
    pos_kernel<<<(NE / 4) / 256, 256, 0, stream>>>(dst, deg, pos);
    tilesum_kernel<<<NT, 256, 0, stream>>>(deg, tilesum);
    tilescan_kernel<<<1, 256, 0, stream>>>(tilesum, tileoff, rowptr);
    rowptr_kernel<<<NT, 256, 0, stream>>>(deg, tileoff, rowptr);
    fill_kernel<<<(NE / 4) / 256, 256, 0, stream>>>(src, dst, pos, rowptr, col);
    prep_kernel<<<(NL * DD * DD) / 256, 256, 0, stream>>>(Ws1, Ws2, W1T, W2T);

    const unsigned short* xin = x0bf;
    unsigned short* bufs[2] = {xA, xB};
    for (int l = 0; l < NL; l++) {
        agg_kernel<<<NN / 8, 256, 0, stream>>>(xin, rowptr, col, hpre);
        unsigned short* xout = bufs[l & 1];
        mlp_kernel<<<(NN + 63) / 64, 256, 0, stream>>>(hpre, W1T + l * DD * DD, bs1 + l * DD,
                                                       W2T + l * DD * DD, bs2 + l * DD, xout);
        xin = xout;
    }
    pool_kernel<<<NG, 128, 0, stream>>>(xin, batch, out);
}